// Round 6
// baseline (202.714 us; speedup 1.0000x reference)
//
#include <hip/hip_runtime.h>

typedef unsigned short u16;
typedef unsigned int u32;
typedef __bf16 bf16x8 __attribute__((ext_vector_type(8)));
typedef float f32x4 __attribute__((ext_vector_type(4)));
typedef u16 u16x4 __attribute__((ext_vector_type(4)));

#define GL2LDS16(g, l)                                                         \
    __builtin_amdgcn_global_load_lds(                                          \
        (__attribute__((address_space(1))) const void*)(g),                    \
        (__attribute__((address_space(3))) void*)(l), 16, 0, 0)

#define SYNC_VM(n) asm volatile("s_waitcnt vmcnt(" #n ")\ns_barrier" ::: "memory")
#define BAR()      asm volatile("s_barrier" ::: "memory")

// ---------- helpers ----------
__device__ __forceinline__ u16 f2bf(float f) {
    union { float f; u32 u; } x; x.f = f;
    u32 r = x.u + 0x7FFFu + ((x.u >> 16) & 1u);   // RNE (no NaNs here)
    return (u16)(r >> 16);
}

// pack 2 floats -> 2 bf16 in one u32 (round-half-up: add 0x8000 then take hi16)
__device__ __forceinline__ u32 pack2bf(float f0, float f1) {
    union { float f; u32 u; } a, b;
    a.f = f0; b.f = f1;
    return __builtin_amdgcn_perm(b.u + 0x8000u, a.u + 0x8000u, 0x07060302u);
}

// fold softmax scale + log2(e) into Q fragments (score then used with exp2)
__device__ __forceinline__ bf16x8 scale_frag(bf16x8 v) {
#pragma unroll
    for (int i = 0; i < 8; ++i) v[i] = (__bf16)((float)v[i] * 0.1803368801f);
    return v;
}

// ---------- fused fp32 -> bf16 convert (x | qkv | wo -> contiguous ws) ----------
__global__ __launch_bounds__(256) void convert_all_kernel(const float* __restrict__ x,
                                                          const float* __restrict__ qkv,
                                                          const float* __restrict__ wo,
                                                          u16* __restrict__ out) {
    int i = (blockIdx.x * 256 + threadIdx.x) * 4;
    const float* src;
    int off;
    if (i < 4194304)      { src = x;   off = i; }
    else if (i < 7340032) { src = qkv; off = i - 4194304; }
    else                  { src = wo;  off = i - 7340032; }
    float4 v = *(const float4*)(src + off);
    u16x4 o;
    o.x = f2bf(v.x); o.y = f2bf(v.y); o.z = f2bf(v.z); o.w = f2bf(v.w);
    *(u16x4*)(out + i) = o;
}

// ---------- GEMM: C[M,N] = A[M,K] * B[N,K]^T, bf16, double-buffered pipeline ----------
template <int TM, bool OUT_BF16>
__global__ __launch_bounds__(256) void gemm_bt(const u16* __restrict__ A,
                                               const u16* __restrict__ B,
                                               void* __restrict__ Cout,
                                               int M, int N, int K) {
    constexpr int MI = TM / 32;
    __shared__ u16 As[2][TM * 32];
    __shared__ u16 Bs[2][128 * 32];
    const int tid = threadIdx.x;
    const int w = tid >> 6, lane = tid & 63, ln = lane & 15, qd = lane >> 4;
    const int wr = w >> 1, wc = w & 1;
    const int m0 = blockIdx.y * TM, n0 = blockIdx.x * 128;

    const int srow = tid >> 2, scol = (tid & 3) * 8;
    const u16* Abase = A + (size_t)(m0 + srow) * K + scol;
    const u16* Bbase = B + (size_t)(n0 + srow) * K + scol;

    f32x4 acc[MI][4] = {};
    const int nsteps = K >> 5;

#pragma unroll
    for (int it = 0; it < TM / 64; ++it)
        GL2LDS16(Abase + (size_t)(it * 64) * K, &As[0][(tid + it * 256) * 8]);
#pragma unroll
    for (int it = 0; it < 2; ++it)
        GL2LDS16(Bbase + (size_t)(it * 64) * K, &Bs[0][(tid + it * 256) * 8]);

    for (int s = 0; s < nsteps; ++s) {
        const u16* Ab = As[s & 1];
        const u16* Bb = Bs[s & 1];
        if (s + 1 < nsteps) {
            const int nk = (s + 1) << 5;
            const int nb = (s + 1) & 1;
#pragma unroll
            for (int it = 0; it < TM / 64; ++it)
                GL2LDS16(Abase + (size_t)(it * 64) * K + nk, &As[nb][(tid + it * 256) * 8]);
#pragma unroll
            for (int it = 0; it < 2; ++it)
                GL2LDS16(Bbase + (size_t)(it * 64) * K + nk, &Bs[nb][(tid + it * 256) * 8]);
            if constexpr (TM == 128) SYNC_VM(4); else SYNC_VM(3);
        } else {
            SYNC_VM(0);
        }

        bf16x8 af[MI], bfr[4];
#pragma unroll
        for (int i = 0; i < MI; ++i)
            af[i] = *(const bf16x8*)&Ab[(wr * (TM / 2) + i * 16 + ln) * 32 + qd * 8];
#pragma unroll
        for (int j = 0; j < 4; ++j)
            bfr[j] = *(const bf16x8*)&Bb[(wc * 64 + j * 16 + ln) * 32 + qd * 8];
#pragma unroll
        for (int i = 0; i < MI; ++i)
#pragma unroll
            for (int j = 0; j < 4; ++j)
                acc[i][j] = __builtin_amdgcn_mfma_f32_16x16x32_bf16(af[i], bfr[j], acc[i][j], 0, 0, 0);
        BAR();
    }

#pragma unroll
    for (int i = 0; i < MI; ++i)
#pragma unroll
        for (int j = 0; j < 4; ++j)
#pragma unroll
            for (int r = 0; r < 4; ++r) {
                int row = m0 + wr * (TM / 2) + i * 16 + qd * 4 + r;
                int col = n0 + wc * 64 + j * 16 + ln;
                float v = acc[i][j][r];
                if constexpr (OUT_BF16)
                    ((u16*)Cout)[(size_t)row * N + col] = f2bf(v);
                else
                    ((float*)Cout)[(size_t)row * N + col] = v;
            }
}

// ---------- V transpose: QKV[b*2048+s][2048 + h*64 + d] -> VtG[(b*16+h)*64+d][s] ----------
__global__ __launch_bounds__(256) void vtrans_kernel(const u16* __restrict__ QKV,
                                                     u16* __restrict__ VtG) {
    __shared__ u16 T[64 * 72];
    const int tid = threadIdx.x;
    const int bh = blockIdx.y;
    const int b = bh >> 4, h = bh & 15;
    const int s0 = blockIdx.x * 64;
#pragma unroll
    for (int it = 0; it < 2; ++it) {
        int idx = it * 256 + tid;
        int sl = idx >> 3, dg = (idx & 7) << 3;
        union { uint4 v; u16 u[8]; } raw;
        raw.v = *(const uint4*)(QKV + (size_t)(b * 2048 + s0 + sl) * 3072 + 2048 + h * 64 + dg);
#pragma unroll
        for (int j = 0; j < 8; ++j) T[(dg + j) * 72 + sl] = raw.u[j];
    }
    __syncthreads();
#pragma unroll
    for (int it = 0; it < 2; ++it) {
        int idx = it * 256 + tid;
        int d = idx >> 3, sg = (idx & 7) << 3;
        *(uint4*)(VtG + ((size_t)(bh * 64 + d)) * 2048 + s0 + sg) = *(uint4*)&T[d * 72 + sg];
    }
}

// ---------- flash attention (causal): 128-thr blocks, paired 32-row q-tiles ----------
// Pair (qtA = blockIdx.x, qtB = 63-blockIdx.x) of 32-row tiles: uniform 33
// tile-chunks/block, grid 1024 = 4 blocks/CU (36 KB LDS). Each wave carries
// 16 q of each tile. Transposed scores (S^T = K Q^T), exp2 softmax with scale
// folded into Q, no max subtraction, GL2LDS double-buffer, XOR-swizzled LDS,
// perm-packed bf16 stores.
__global__ __launch_bounds__(128) void attn_kernel(const u16* __restrict__ QKV,
                                                   const u16* __restrict__ VtG,
                                                   u16* __restrict__ AO) {
    __shared__ u16 Ks[2][64 * 64];     // [key][dh], swizzled
    __shared__ u16 Vts[2][64 * 64];    // [dh][key], swizzled
    __shared__ u16 Pls[2][16 * 64];    // per wave P[q][key]; reused B then A

    const int tid = threadIdx.x;
    const int w = tid >> 6, lane = tid & 63, ln = lane & 15, qd = lane >> 4;
    const int b = blockIdx.z, h = blockIdx.y;
    const int qtA = blockIdx.x;        // 0..31 (light 32-row tile)
    const int qtB = 63 - qtA;          // 32..63 (heavy)
    const int XA = qtA * 32 + w * 16;  // wave's min q row per tile
    const int XB = qtB * 32 + w * 16;
    const int myqA = XA + ln, myqB = XB + ln;
    const int bh = b * 16 + h;
    const int swz = ln & 7;
    const int nch = (qtB >> 1) + 1;    // 64-key chunks covering tile B

    // staging: 4 slots/thread per matrix; slot = i*128+tid, row = i*16 + (tid>>3),
    // source colgroup swizzled by row&7 = (tid>>3)&7
    const int sr0 = tid >> 3;
    const int sg = (tid & 7) ^ (sr0 & 7);
    const u16* ksrc = QKV + (size_t)(b * 2048 + sr0) * 3072 + 1024 + h * 64 + sg * 8;
    const u16* vsrc = VtG + (size_t)(bh * 64 + sr0) * 2048 + sg * 8;

#pragma unroll
    for (int i = 0; i < 4; ++i) {
        GL2LDS16(ksrc + (size_t)(i * 16) * 3072, &Ks[0][(i * 128 + tid) * 8]);
        GL2LDS16(vsrc + (size_t)(i * 16) * 2048, &Vts[0][(i * 128 + tid) * 8]);
    }

    // Q B-frags for both tiles, scale*log2e folded in
    const u16* qpA = QKV + (size_t)(b * 2048 + myqA) * 3072 + h * 64;
    const u16* qpB = QKV + (size_t)(b * 2048 + myqB) * 3072 + h * 64;
    bf16x8 qfA0 = scale_frag(*(const bf16x8*)(qpA + qd * 8));
    bf16x8 qfA1 = scale_frag(*(const bf16x8*)(qpA + 32 + qd * 8));
    bf16x8 qfB0 = scale_frag(*(const bf16x8*)(qpB + qd * 8));
    bf16x8 qfB1 = scale_frag(*(const bf16x8*)(qpB + 32 + qd * 8));

    f32x4 oA[4] = {}, oB[4] = {};
    float lA = 0.f, lB = 0.f;
    u16* Pw = Pls[w];

    for (int c = 0; c < nch; ++c) {
        if (c + 1 < nch) {
            const int k1 = (c + 1) * 64;
            const int nb = (c + 1) & 1;
#pragma unroll
            for (int i = 0; i < 4; ++i) {
                GL2LDS16(ksrc + (size_t)(k1 + i * 16) * 3072, &Ks[nb][(i * 128 + tid) * 8]);
                GL2LDS16(vsrc + (size_t)(i * 16) * 2048 + k1, &Vts[nb][(i * 128 + tid) * 8]);
            }
            SYNC_VM(8);
        } else {
            SYNC_VM(0);
        }
        const u16* Kb = Ks[c & 1];
        const u16* Vb = Vts[c & 1];
        const bool actA = (c * 64 <= XA + 15);   // wave-uniform

        // ---- S^T = K Q^T, K frags shared between tiles ----
        f32x4 sA[4], sB[4];
#pragma unroll
        for (int kt = 0; kt < 4; ++kt) {
            const u16* kr = Kb + (kt * 16 + ln) * 64;
            bf16x8 kf0 = *(const bf16x8*)(kr + ((qd ^ swz) * 8));
            bf16x8 kf1 = *(const bf16x8*)(kr + (((qd + 4) ^ swz) * 8));
            f32x4 z = {0.f, 0.f, 0.f, 0.f};
            z = __builtin_amdgcn_mfma_f32_16x16x32_bf16(kf0, qfB0, z, 0, 0, 0);
            z = __builtin_amdgcn_mfma_f32_16x16x32_bf16(kf1, qfB1, z, 0, 0, 0);
            sB[kt] = z;
            if (actA) {
                f32x4 y = {0.f, 0.f, 0.f, 0.f};
                y = __builtin_amdgcn_mfma_f32_16x16x32_bf16(kf0, qfA0, y, 0, 0, 0);
                y = __builtin_amdgcn_mfma_f32_16x16x32_bf16(kf1, qfA1, y, 0, 0, 0);
                sA[kt] = y;
            }
        }

        // ---- tile B: mask (near-diagonal chunks only) + exp2 + pack ----
        if (c * 64 + 63 > XB) {
#pragma unroll
            for (int kt = 0; kt < 4; ++kt)
#pragma unroll
                for (int r = 0; r < 4; ++r) {
                    int key = c * 64 + kt * 16 + qd * 4 + r;
                    if (key > myqB) sB[kt][r] = -1e30f;
                }
        }
#pragma unroll
        for (int kt = 0; kt < 4; ++kt) {
            float p0 = exp2f(sB[kt][0]), p1 = exp2f(sB[kt][1]);
            float p2 = exp2f(sB[kt][2]), p3 = exp2f(sB[kt][3]);
            lB += (p0 + p1) + (p2 + p3);
            uint2 pk = {pack2bf(p0, p1), pack2bf(p2, p3)};
            int g = kt * 2 + (qd >> 1);
            *(uint2*)&Pw[ln * 64 + ((g ^ swz) * 8) + (qd & 1) * 4] = pk;
        }
        bf16x8 pfB0 = *(const bf16x8*)&Pw[ln * 64 + ((qd ^ swz) * 8)];
        bf16x8 pfB1 = *(const bf16x8*)&Pw[ln * 64 + (((qd + 4) ^ swz) * 8)];

        // ---- tile A: same, reusing Pw (same-wave in-order DS => safe WAR) ----
        bf16x8 pfA0, pfA1;
        if (actA) {
            if (c * 64 + 63 > XA) {
#pragma unroll
                for (int kt = 0; kt < 4; ++kt)
#pragma unroll
                    for (int r = 0; r < 4; ++r) {
                        int key = c * 64 + kt * 16 + qd * 4 + r;
                        if (key > myqA) sA[kt][r] = -1e30f;
                    }
            }
#pragma unroll
            for (int kt = 0; kt < 4; ++kt) {
                float p0 = exp2f(sA[kt][0]), p1 = exp2f(sA[kt][1]);
                float p2 = exp2f(sA[kt][2]), p3 = exp2f(sA[kt][3]);
                lA += (p0 + p1) + (p2 + p3);
                uint2 pk = {pack2bf(p0, p1), pack2bf(p2, p3)};
                int g = kt * 2 + (qd >> 1);
                *(uint2*)&Pw[ln * 64 + ((g ^ swz) * 8) + (qd & 1) * 4] = pk;
            }
            pfA0 = *(const bf16x8*)&Pw[ln * 64 + ((qd ^ swz) * 8)];
            pfA1 = *(const bf16x8*)&Pw[ln * 64 + (((qd + 4) ^ swz) * 8)];
        }

        // ---- PV for both tiles, V frags shared ----
#pragma unroll
        for (int dt = 0; dt < 4; ++dt) {
            const u16* vr = Vb + (dt * 16 + ln) * 64;
            bf16x8 vf0 = *(const bf16x8*)(vr + ((qd ^ swz) * 8));
            bf16x8 vf1 = *(const bf16x8*)(vr + (((qd + 4) ^ swz) * 8));
            oB[dt] = __builtin_amdgcn_mfma_f32_16x16x32_bf16(vf0, pfB0, oB[dt], 0, 0, 0);
            oB[dt] = __builtin_amdgcn_mfma_f32_16x16x32_bf16(vf1, pfB1, oB[dt], 0, 0, 0);
            if (actA) {
                oA[dt] = __builtin_amdgcn_mfma_f32_16x16x32_bf16(vf0, pfA0, oA[dt], 0, 0, 0);
                oA[dt] = __builtin_amdgcn_mfma_f32_16x16x32_bf16(vf1, pfA1, oA[dt], 0, 0, 0);
            }
        }
        BAR();
    }

    // ---- deferred l reductions, normalize, perm-packed stores ----
    lA += __shfl_xor(lA, 16); lA += __shfl_xor(lA, 32);
    lB += __shfl_xor(lB, 16); lB += __shfl_xor(lB, 32);
    float invA = 1.0f / lA, invB = 1.0f / lB;
#pragma unroll
    for (int dt = 0; dt < 4; ++dt) {
        uint2 ovA = {pack2bf(oA[dt][0] * invA, oA[dt][1] * invA),
                     pack2bf(oA[dt][2] * invA, oA[dt][3] * invA)};
        *(uint2*)&AO[(size_t)(b * 2048 + myqA) * 1024 + h * 64 + dt * 16 + qd * 4] = ovA;
        uint2 ovB = {pack2bf(oB[dt][0] * invB, oB[dt][1] * invB),
                     pack2bf(oB[dt][2] * invB, oB[dt][3] * invB)};
        *(uint2*)&AO[(size_t)(b * 2048 + myqB) * 1024 + h * 64 + dt * 16 + qd * 4] = ovB;
    }
}

// ---------- launch ----------
extern "C" void kernel_launch(void* const* d_in, const int* in_sizes, int n_in,
                              void* d_out, int out_size, void* d_ws, size_t ws_size,
                              hipStream_t stream) {
    const float* x   = (const float*)d_in[0];   // [2,2048,1024]
    const float* qkv = (const float*)d_in[1];   // [3072,1024]
    const float* wo  = (const float*)d_in[2];   // [1024,1024]
    float* out = (float*)d_out;                 // [2,2048,1024] fp32

    char* ws = (char*)d_ws;
    u16* xb   = (u16*)(ws + 0);            //  8 MB : x bf16      [4096,1024]
    u16* qkvb = (u16*)(ws + 8388608);      //  6 MB : qkv bf16    [3072,1024]
    u16* wob  = (u16*)(ws + 14680064);     //  2 MB : wo bf16     [1024,1024]
    u16* QKVo = (u16*)(ws + 16777216);     // 24 MB : QKV out bf16[4096,3072]
    u16* AO   = (u16*)(ws + 41943040);     //  8 MB : attn out    [4096,1024]
    u16* VtG  = (u16*)(ws + 0);            //  8 MB : V^T (aliases xb — dead after QKV GEMM)

    convert_all_kernel<<<8192, 256, 0, stream>>>(x, qkv, wo, xb);

    gemm_bt<128, true><<<dim3(24, 32), 256, 0, stream>>>(xb, qkvb, QKVo, 4096, 3072, 1024);

    vtrans_kernel<<<dim3(32, 32), 256, 0, stream>>>(QKVo, VtG);

    attn_kernel<<<dim3(32, 16, 2), 128, 0, stream>>>(QKVo, VtG, AO);

    gemm_bt<64, false><<<dim3(8, 64), 256, 0, stream>>>(AO, wob, out, 4096, 1024, 1024);
}